// Round 8
// baseline (120.738 us; speedup 1.0000x reference)
//
#include <hip/hip_runtime.h>

#define NS 65536
#define DD 32
#define RR 128
#define SPB 16            // samples per block
#define STR 132           // padded LDS row stride (floats)

typedef float f2 __attribute__((ext_vector_type(2)));

// One packed f32 FMA: d = a*b + c elementwise on a 2-float VGPR pair.
static __device__ __forceinline__ f2 pkfma(f2 a, f2 b, f2 c) {
    f2 d;
    asm("v_pk_fma_f32 %0, %1, %2, %3" : "=v"(d) : "v"(a), "v"(b), "v"(c));
    return d;
}

// R12 = R11 + dual-pipe x-operand feed.
// Evidence: R4/R7/R10/R11 all pin at 45.5us while VALU-busy time varies 15-21us
// (pk_fma halved FMA issue, dur unmoved) => not issue-bound. The common factor
// of R7-R11: ALL x operands flow through the per-CU LDS pipe as wave-uniform
// ds_read_b128 broadcasts (128/wave/tile). Per CU-generation that is ~5-12Kcy
// of LDS-pipe time vs ~3Kcy generation time at the ~1.1GHz effective clock:
// the LDS pipe is saturated, waves sit in lgkmcnt, VALUBusy ~35% = FMA/feed.
// Fix: feed half-sample 0 from LDS (unchanged) and half-sample 1 from global X
// via L1 (prologue staging already leaves the 2KB tile L1-resident; uniform
// address = one-line broadcast; vmcnt in-order, covered by the qa/qb pipeline).
// Address laundered through a VGPR so the compiler cannot scalarize to SMEM
// (R4 trap); one base + small offsets avoids R5's compiler mangling.
// Same float values, same op order => bit-identical outputs.
__global__ __launch_bounds__(128, 3) void anfis_main(
    const float* __restrict__ X, const float* __restrict__ A,
    const float* __restrict__ B, const float* __restrict__ C,
    float* __restrict__ out_pred, float* __restrict__ out_str,
    float* __restrict__ out_norm)
{
    __shared__ float SBUF[SPB * STR];   // strengths, row = sample-in-block
    __shared__ float PBUF[SPB * STR];   // strength * rule_out
    __shared__ float XT[SPB * DD];      // block's X tile (512 floats)
    __shared__ float pS[SPB][8];
    __shared__ float pD[SPB][8];
    __shared__ float scale_lds[SPB];

    const int tid   = threadIdx.x;      // rule id
    const int nbase = blockIdx.x * SPB;

    // ---- stage X tile to LDS (coalesced 2KB, 1 float4/thread).
    //      Side effect: the whole tile is now L1-resident for the VMEM half. ----
    ((float4*)XT)[tid] = ((const float4*)(X + (size_t)nbase * DD))[tid];

    // Laundered VGPR zero: keeps the main-loop X address vector (VMEM/L1,
    // vmcnt-ordered) instead of scalarizing to SMEM.
    int vzero = 0;
    asm("" : "+v"(vzero));
    const float* xg = X + (size_t)nbase * DD + vzero;

    // ---- per-thread rule params -> VGPR pairs (f2), loaded once ----
    f2 w01_[8], w23_[8], n01_[8], n23_[8], c01_[8], c23_[8];
    float bias;
    {
        const float4* av = (const float4*)(A + tid * DD);
        const float4* bv = (const float4*)(B + tid * DD);
        #pragma unroll
        for (int i = 0; i < 8; ++i) {
            float4 va = av[i], vb = bv[i];
            float w0 = 0.8493218003f * __builtin_amdgcn_rcpf(fmaxf(vb.x, 1e-8f));
            float w1 = 0.8493218003f * __builtin_amdgcn_rcpf(fmaxf(vb.y, 1e-8f));
            float w2 = 0.8493218003f * __builtin_amdgcn_rcpf(fmaxf(vb.z, 1e-8f));
            float w3 = 0.8493218003f * __builtin_amdgcn_rcpf(fmaxf(vb.w, 1e-8f));
            w01_[i] = f2{w0, w1};            w23_[i] = f2{w2, w3};
            n01_[i] = f2{-va.x * w0, -va.y * w1};
            n23_[i] = f2{-va.z * w2, -va.w * w3};
            c01_[i] = f2{C[tid * (DD + 1) + 4*i + 0], C[tid * (DD + 1) + 4*i + 1]};
            c23_[i] = f2{C[tid * (DD + 1) + 4*i + 2], C[tid * (DD + 1) + 4*i + 3]};
        }
        bias = C[tid * (DD + 1) + DD];
    }
    __syncthreads();                    // XT visible to both waves

    // Pin params: forbid rematerialization/reload inside the sample loop.
    #pragma unroll
    for (int i = 0; i < 8; ++i)
        asm("" : "+v"(w01_[i]), "+v"(w23_[i]), "+v"(n01_[i]),
                 "+v"(n23_[i]), "+v"(c01_[i]), "+v"(c23_[i]));
    asm("" : "+v"(bias));

    // half 0 (dims 0-15) of sample jj from LDS: 4 wave-uniform ds_read_b128.
    #define LOADH_LDS(buf, jj) { _Pragma("unroll") \
        for (int g = 0; g < 4; ++g) \
            buf[g] = *(const float4*)&XT[(jj) * DD + g * 4]; }

    // half 1 (dims 16-31) of sample jj from global/L1: 4 uniform-address
    // global_load_dwordx4 (one 128B line broadcast; line is L1-hot from staging).
    #define LOADH_G(buf, jj) { _Pragma("unroll") \
        for (int g = 0; g < 4; ++g) \
            buf[g] = *(const float4*)(xg + (jj) * DD + 16 + g * 4); }

    // process 4 groups (16 dims) starting at group gbase; packed slots keep the
    // exact per-slot op sequence of the scalar version (s0..s3 <-> s01,s23).
    #define COMPUTEH(buf, gbase) { _Pragma("unroll") \
        for (int g = 0; g < 4; ++g) { \
            const int gi = (gbase) + g; \
            const f2* xp2 = (const f2*)&buf[g]; \
            f2 x01 = xp2[0], x23 = xp2[1]; \
            f2 t01 = pkfma(x01, w01_[gi], n01_[gi]); \
            s01 = pkfma(t01, t01, s01); \
            r01 = pkfma(x01, c01_[gi], r01); \
            f2 t23 = pkfma(x23, w23_[gi], n23_[gi]); \
            s23 = pkfma(t23, t23, s23); \
            r23 = pkfma(x23, c23_[gi], r23); \
        } }

    float4 qa[4], qb[4];
    LOADH_LDS(qa, 0)
    #pragma unroll 2
    for (int j = 0; j < SPB; ++j) {
        f2 s01 = f2{0.f, 0.f}, s23 = f2{0.f, 0.f};
        f2 r01 = f2{bias, 0.f}, r23 = f2{0.f, 0.f};
        LOADH_G(qb, j)                      // issue VMEM reads for 2nd half of j
        COMPUTEH(qa, 0)                     // pk-FMAs cover the L1 latency
        LOADH_LDS(qa, (j + 1) & (SPB - 1))  // issue LDS reads for 1st half of j+1
        COMPUTEH(qb, 4)
        float st = __builtin_amdgcn_exp2f(-((s01.x + s01.y) + (s23.x + s23.y)));
        float ro = (r01.x + r01.y) + (r23.x + r23.y);
        SBUF[j * STR + tid] = st;
        PBUF[j * STR + tid] = st * ro;
    }
    #undef LOADH_LDS
    #undef LOADH_G
    #undef COMPUTEH
    __syncthreads();

    // ---- per-sample sums over rules: 128 threads = 16 samples x 8 octants ----
    {
        int s = tid >> 3, o = tid & 7;      // 16B-group o covers 16 floats
        const float4* srow = (const float4*)&SBUF[s * STR + o * 16];
        const float4* prow = (const float4*)&PBUF[s * STR + o * 16];
        float ss = 0.f, dd = 0.f;
        #pragma unroll
        for (int k = 0; k < 4; ++k) {
            float4 v = srow[k]; ss += (v.x + v.y) + (v.z + v.w);
            float4 p = prow[k]; dd += (p.x + p.y) + (p.z + p.w);
        }
        pS[s][o] = ss; pD[s][o] = dd;
    }
    __syncthreads();
    float predv = 0.f;
    if (tid < SPB) {
        float ss = 0.f, dd = 0.f;
        #pragma unroll
        for (int o = 0; o < 8; ++o) { ss += pS[tid][o]; dd += pD[tid][o]; }
        float sc = 1.0f / (ss + 1e-8f);
        predv = dd * sc;                // store deferred past the barrier
        scale_lds[tid] = sc;
    }
    __syncthreads();
    if (tid < SPB) out_pred[nbase + tid] = predv;

    // ---- flush strengths + normalized, float4-coalesced ----
    #pragma unroll
    for (int it = 0; it < 4; ++it) {
        int f   = it * 128 + tid;       // float4 index over 16x32 tile
        int row = f >> 5;
        int col = f & 31;
        float4 v = *(const float4*)&SBUF[row * STR + col * 4];
        float sc = scale_lds[row];
        size_t base = ((size_t)(nbase + row)) * RR + col * 4;
        *(float4*)(out_str  + base) = v;
        *(float4*)(out_norm + base) = make_float4(v.x * sc, v.y * sc, v.z * sc, v.w * sc);
    }
}

extern "C" void kernel_launch(void* const* d_in, const int* in_sizes, int n_in,
                              void* d_out, int out_size, void* d_ws, size_t ws_size,
                              hipStream_t stream) {
    const float* X = (const float*)d_in[0];
    const float* A = (const float*)d_in[1];
    const float* B = (const float*)d_in[2];
    const float* C = (const float*)d_in[3];

    float* pred = (float*)d_out;
    float* str  = pred + NS;
    float* nrm  = str + (size_t)NS * RR;

    anfis_main<<<dim3(NS / SPB), dim3(128), 0, stream>>>(X, A, B, C, pred, str, nrm);
}

// Round 9
// 106.201 us; speedup vs baseline: 1.1369x; 1.1369x over previous
//
#include <hip/hip_runtime.h>

#define NS 65536
#define DD 32
#define RR 128
#define SPB 32            // samples per block (R13: 16 -> 32)
#define STR 132           // padded LDS row stride (floats)

typedef float f2 __attribute__((ext_vector_type(2)));

// One packed f32 FMA: d = a*b + c elementwise on a 2-float VGPR pair.
static __device__ __forceinline__ f2 pkfma(f2 a, f2 b, f2 c) {
    f2 d;
    asm("v_pk_fma_f32 %0, %1, %2, %3" : "=v"(d) : "v"(a), "v"(b), "v"(c));
    return d;
}

// R13 = R11 (pure-LDS feed, pk_fma, deferred pred store) with SPB 16->32.
// Fact set: dur pinned ~45.5us across 5 different kernels; VALU-busy 15-28us
// with no effect on dur (R11); prologue count neutral (R10); feed pipe refuted
// (R6 vs R7 identical; R12's VMEM feed regressed 45->60 => in-loop latency is
// NOT covered at 2 waves/SIMD). Residency arithmetic: occupancy 25% = ~3.7
// blocks/CU => block lifetime ~10.6us vs ~3us of issue => ~8us of PER-BLOCK
// fixed stalls (cold-X staging vmcnt, 4-phase barrier convoy, flush-store
// drain, launch/drain). R13 halves blocks (2048) and per-sample overhead:
// 2x work per block at the SAME ~40KB/4-blocks-per-CU residency we already
// measure. Per-(sample,rule) arithmetic and reduction orders untouched =>
// bit-identical outputs.
__global__ __launch_bounds__(128, 3) void anfis_main(
    const float* __restrict__ X, const float* __restrict__ A,
    const float* __restrict__ B, const float* __restrict__ C,
    float* __restrict__ out_pred, float* __restrict__ out_str,
    float* __restrict__ out_norm)
{
    __shared__ float SBUF[SPB * STR];   // strengths, row = sample-in-block
    __shared__ float PBUF[SPB * STR];   // strength * rule_out
    __shared__ float XT[SPB * DD];      // block's X tile (4KB)
    __shared__ float pS[SPB][8];
    __shared__ float pD[SPB][8];
    __shared__ float scale_lds[SPB];

    const int tid   = threadIdx.x;      // rule id
    const int nbase = blockIdx.x * SPB;

    // ---- stage X tile to LDS (coalesced 4KB, 2 float4/thread) ----
    {
        const float4* xs = (const float4*)(X + (size_t)nbase * DD);
        ((float4*)XT)[tid]       = xs[tid];
        ((float4*)XT)[tid + 128] = xs[tid + 128];
    }

    // ---- per-thread rule params -> VGPR pairs (f2), loaded once ----
    f2 w01_[8], w23_[8], n01_[8], n23_[8], c01_[8], c23_[8];
    float bias;
    {
        const float4* av = (const float4*)(A + tid * DD);
        const float4* bv = (const float4*)(B + tid * DD);
        #pragma unroll
        for (int i = 0; i < 8; ++i) {
            float4 va = av[i], vb = bv[i];
            float w0 = 0.8493218003f * __builtin_amdgcn_rcpf(fmaxf(vb.x, 1e-8f));
            float w1 = 0.8493218003f * __builtin_amdgcn_rcpf(fmaxf(vb.y, 1e-8f));
            float w2 = 0.8493218003f * __builtin_amdgcn_rcpf(fmaxf(vb.z, 1e-8f));
            float w3 = 0.8493218003f * __builtin_amdgcn_rcpf(fmaxf(vb.w, 1e-8f));
            w01_[i] = f2{w0, w1};            w23_[i] = f2{w2, w3};
            n01_[i] = f2{-va.x * w0, -va.y * w1};
            n23_[i] = f2{-va.z * w2, -va.w * w3};
            c01_[i] = f2{C[tid * (DD + 1) + 4*i + 0], C[tid * (DD + 1) + 4*i + 1]};
            c23_[i] = f2{C[tid * (DD + 1) + 4*i + 2], C[tid * (DD + 1) + 4*i + 3]};
        }
        bias = C[tid * (DD + 1) + DD];
    }
    __syncthreads();                    // XT visible to both waves

    // Pin params: forbid rematerialization/reload inside the sample loop.
    #pragma unroll
    for (int i = 0; i < 8; ++i)
        asm("" : "+v"(w01_[i]), "+v"(w23_[i]), "+v"(n01_[i]),
                 "+v"(n23_[i]), "+v"(c01_[i]), "+v"(c23_[i]));
    asm("" : "+v"(bias));

    // half-sample (16 dims) of sample jj, half hh: 4 wave-uniform ds_read_b128
    // (same-address broadcast, conflict-free).
    #define LOADH(buf, jj, hh) { _Pragma("unroll") \
        for (int g = 0; g < 4; ++g) \
            buf[g] = *(const float4*)&XT[(jj) * DD + (hh) * 16 + g * 4]; }

    // 4 groups (16 dims) from group gbase; packed slots keep the exact per-slot
    // op sequence of the scalar version (s0..s3 <-> s01,s23) -> bit-identical.
    #define COMPUTEH(buf, gbase) { _Pragma("unroll") \
        for (int g = 0; g < 4; ++g) { \
            const int gi = (gbase) + g; \
            const f2* xp2 = (const f2*)&buf[g]; \
            f2 x01 = xp2[0], x23 = xp2[1]; \
            f2 t01 = pkfma(x01, w01_[gi], n01_[gi]); \
            s01 = pkfma(t01, t01, s01); \
            r01 = pkfma(x01, c01_[gi], r01); \
            f2 t23 = pkfma(x23, w23_[gi], n23_[gi]); \
            s23 = pkfma(t23, t23, s23); \
            r23 = pkfma(x23, c23_[gi], r23); \
        } }

    float4 qa[4], qb[4];
    LOADH(qa, 0, 0)
    #pragma unroll 2
    for (int j = 0; j < SPB; ++j) {
        f2 s01 = f2{0.f, 0.f}, s23 = f2{0.f, 0.f};
        f2 r01 = f2{bias, 0.f}, r23 = f2{0.f, 0.f};
        LOADH(qb, j, 1)                     // issue reads for 2nd half of j
        COMPUTEH(qa, 0)                     // pk-FMAs cover the LDS latency
        LOADH(qa, (j + 1) & (SPB - 1), 0)   // issue reads for 1st half of j+1
        COMPUTEH(qb, 4)
        float st = __builtin_amdgcn_exp2f(-((s01.x + s01.y) + (s23.x + s23.y)));
        float ro = (r01.x + r01.y) + (r23.x + r23.y);
        SBUF[j * STR + tid] = st;
        PBUF[j * STR + tid] = st * ro;
    }
    #undef LOADH
    #undef COMPUTEH
    __syncthreads();

    // ---- per-sample sums over rules: 32 samples x 8 octants = 256 slots,
    //      2 passes over 128 threads (same octant grouping -> identical sums) ----
    #pragma unroll
    for (int p = 0; p < 2; ++p) {
        int s = (tid >> 3) + p * 16, o = tid & 7;   // 16B-group o covers 16 floats
        const float4* srow = (const float4*)&SBUF[s * STR + o * 16];
        const float4* prow = (const float4*)&PBUF[s * STR + o * 16];
        float ss = 0.f, dd = 0.f;
        #pragma unroll
        for (int k = 0; k < 4; ++k) {
            float4 v = srow[k]; ss += (v.x + v.y) + (v.z + v.w);
            float4 p2 = prow[k]; dd += (p2.x + p2.y) + (p2.z + p2.w);
        }
        pS[s][o] = ss; pD[s][o] = dd;
    }
    __syncthreads();
    float predv = 0.f;
    if (tid < SPB) {
        float ss = 0.f, dd = 0.f;
        #pragma unroll
        for (int o = 0; o < 8; ++o) { ss += pS[tid][o]; dd += pD[tid][o]; }
        float sc = 1.0f / (ss + 1e-8f);
        predv = dd * sc;                // store deferred past the barrier
        scale_lds[tid] = sc;
    }
    __syncthreads();
    if (tid < SPB) out_pred[nbase + tid] = predv;

    // ---- flush strengths + normalized, float4-coalesced (32x32 float4 tile) ----
    #pragma unroll
    for (int it = 0; it < 8; ++it) {
        int f   = it * 128 + tid;       // float4 index over 32x32 tile
        int row = f >> 5;
        int col = f & 31;
        float4 v = *(const float4*)&SBUF[row * STR + col * 4];
        float sc = scale_lds[row];
        size_t base = ((size_t)(nbase + row)) * RR + col * 4;
        *(float4*)(out_str  + base) = v;
        *(float4*)(out_norm + base) = make_float4(v.x * sc, v.y * sc, v.z * sc, v.w * sc);
    }
}

extern "C" void kernel_launch(void* const* d_in, const int* in_sizes, int n_in,
                              void* d_out, int out_size, void* d_ws, size_t ws_size,
                              hipStream_t stream) {
    const float* X = (const float*)d_in[0];
    const float* A = (const float*)d_in[1];
    const float* B = (const float*)d_in[2];
    const float* C = (const float*)d_in[3];

    float* pred = (float*)d_out;
    float* str  = pred + NS;
    float* nrm  = str + (size_t)NS * RR;

    anfis_main<<<dim3(NS / SPB), dim3(128), 0, stream>>>(X, A, B, C, pred, str, nrm);
}

// Round 10
// 100.288 us; speedup vs baseline: 1.2039x; 1.0590x over previous
//
#include <hip/hip_runtime.h>

#define NS 65536
#define DD 32
#define RR 128
#define SPB 32            // samples per block
#define STR 132           // padded LDS row stride (floats)
#define NBLK (NS / SPB)   // 2048 blocks

typedef float f2 __attribute__((ext_vector_type(2)));

static __device__ __forceinline__ f2 pkfma(f2 a, f2 b, f2 c) {
    f2 d;
    asm("v_pk_fma_f32 %0, %1, %2, %3" : "=v"(d) : "v"(a), "v"(b), "v"(c));
    return d;
}

// neighbor-lane (xor 1) value via DPP quad_perm [1,0,3,2] — VALU pipe only,
// no LDS op, no barrier. Partners are adjacent lanes of the same wave.
static __device__ __forceinline__ float dpp_x1(float x) {
    return __int_as_float(__builtin_amdgcn_update_dpp(
        0, __float_as_int(x), 0xB1 /*quad_perm(1,0,3,2)*/, 0xF, 0xF, true));
}

// R14: split each rule across a LANE PAIR: thread = (rule, dim-half).
// Root cause found for the 45.5us wall: gfx950 unified VGPR+AGPR file. The 97
// pinned params + buffers = ~170 combined regs/thread (CSV VGPR_Count=80 is
// arch-VGPRs only) -> 2 waves/SIMD -> ~3.7 blocks/CU residency — exactly the
// measured 22-26% occupancy. Block lifetime (~10.5us) is latency-dominated at
// that residency, so dur was invariant to issue cuts (R11), feed pipe (R6/R7),
// block count (R10/R13). Fix: 48+1 param regs per thread (dims half split),
// ~105 total demand, (256,4) cap 128 -> 4 waves/SIMD, 2.2x residency.
// Partial s,r are combined with dpp_x1 + add (2 VALU ops each).
// Numerics: data makes ALL outputs ~<=1e-20 (strengths ~ exp(-128)); the
// half-split reduction-order change moves absmax from 8.08e-28 to ~<=1e-25.
__global__ __launch_bounds__(256, 4) void anfis_main(
    const float* __restrict__ X, const float* __restrict__ A,
    const float* __restrict__ B, const float* __restrict__ C,
    float* __restrict__ out_pred, float* __restrict__ out_str,
    float* __restrict__ out_norm)
{
    __shared__ float SBUF[SPB * STR];   // strengths, row = sample-in-block
    __shared__ float PBUF[SPB * STR];   // strength * rule_out
    __shared__ float XT[SPB * DD];      // block's X tile (4KB)
    __shared__ float pS[SPB][8];
    __shared__ float pD[SPB][8];
    __shared__ float scale_lds[SPB];

    const int tid   = threadIdx.x;
    const int rule  = tid >> 1;         // 0..127
    const int half  = tid & 1;          // dim-half: 0 -> dims 0-15, 1 -> 16-31
    const int xoff  = half * 16;
    const int nbase = blockIdx.x * SPB;

    // ---- stage X tile to LDS (4KB, exactly 1 float4 per thread) ----
    ((float4*)XT)[tid] = ((const float4*)(X + (size_t)nbase * DD))[tid];

    // ---- per-thread HALF-rule params -> VGPR pairs (48 + 1 regs) ----
    f2 w01_[4], w23_[4], n01_[4], n23_[4], c01_[4], c23_[4];
    float biasv;
    {
        const float4* av = (const float4*)(A + rule * DD + xoff);
        const float4* bv = (const float4*)(B + rule * DD + xoff);
        const float*  cp = C + rule * (DD + 1) + xoff;
        #pragma unroll
        for (int i = 0; i < 4; ++i) {
            float4 va = av[i], vb = bv[i];
            float w0 = 0.8493218003f * __builtin_amdgcn_rcpf(fmaxf(vb.x, 1e-8f));
            float w1 = 0.8493218003f * __builtin_amdgcn_rcpf(fmaxf(vb.y, 1e-8f));
            float w2 = 0.8493218003f * __builtin_amdgcn_rcpf(fmaxf(vb.z, 1e-8f));
            float w3 = 0.8493218003f * __builtin_amdgcn_rcpf(fmaxf(vb.w, 1e-8f));
            w01_[i] = f2{w0, w1};            w23_[i] = f2{w2, w3};
            n01_[i] = f2{-va.x * w0, -va.y * w1};
            n23_[i] = f2{-va.z * w2, -va.w * w3};
            c01_[i] = f2{cp[4*i + 0], cp[4*i + 1]};
            c23_[i] = f2{cp[4*i + 2], cp[4*i + 3]};
        }
        biasv = half ? C[rule * (DD + 1) + DD] : 0.0f;  // bias lives in half 1
    }
    __syncthreads();                    // XT visible to all 4 waves

    // Pin params: forbid rematerialization/reload inside the sample loop.
    #pragma unroll
    for (int i = 0; i < 4; ++i)
        asm("" : "+v"(w01_[i]), "+v"(w23_[i]), "+v"(n01_[i]),
                 "+v"(n23_[i]), "+v"(c01_[i]), "+v"(c23_[i]));
    asm("" : "+v"(biasv));

    // parity-selected output row buffer: even lanes write strengths,
    // odd lanes write strength*rule_out — one non-divergent ds_write each.
    float* wbuf = half ? PBUF : SBUF;

    // 16 dims of sample jj for this half: 4 ds_read_b128, 2 distinct
    // addresses per wave (2-way broadcast = conflict-free).
    #define LOADQ(buf, jj) { _Pragma("unroll") \
        for (int g = 0; g < 4; ++g) \
            buf[g] = *(const float4*)&XT[(jj) * DD + xoff + g * 4]; }

    // one sample: 24 pk_fma + 2 dpp-reduces + exp2 + 1 LDS write
    #define DOSAMPLE(buf, jj) { \
        f2 s01 = f2{0.f, 0.f}, s23 = f2{0.f, 0.f}; \
        f2 r01 = f2{biasv, 0.f}, r23 = f2{0.f, 0.f}; \
        _Pragma("unroll") \
        for (int g = 0; g < 4; ++g) { \
            const f2* xp2 = (const f2*)&buf[g]; \
            f2 x01 = xp2[0], x23 = xp2[1]; \
            f2 t01 = pkfma(x01, w01_[g], n01_[g]); \
            s01 = pkfma(t01, t01, s01); \
            r01 = pkfma(x01, c01_[g], r01); \
            f2 t23 = pkfma(x23, w23_[g], n23_[g]); \
            s23 = pkfma(t23, t23, s23); \
            r23 = pkfma(x23, c23_[g], r23); \
        } \
        float sh = (s01.x + s01.y) + (s23.x + s23.y); \
        float rh = (r01.x + r01.y) + (r23.x + r23.y); \
        float stot = sh + dpp_x1(sh); \
        float rtot = rh + dpp_x1(rh); \
        float st = __builtin_amdgcn_exp2f(-stot); \
        wbuf[(jj) * STR + rule] = half ? st * rtot : st; }

    float4 qa[4], qb[4];
    LOADQ(qa, 0)
    for (int j = 0; j < SPB; j += 2) {
        LOADQ(qb, j + 1)                    // prefetch j+1 while computing j
        DOSAMPLE(qa, j)
        if (j + 2 < SPB) LOADQ(qa, j + 2)   // prefetch j+2 while computing j+1
        DOSAMPLE(qb, j + 1)
    }
    #undef LOADQ
    #undef DOSAMPLE
    __syncthreads();

    // ---- per-sample sums over rules: 32 samples x 8 octants = 256 threads,
    //      single pass ----
    {
        int s = tid >> 3, o = tid & 7;      // 16B-group o covers 16 floats
        const float4* srow = (const float4*)&SBUF[s * STR + o * 16];
        const float4* prow = (const float4*)&PBUF[s * STR + o * 16];
        float ss = 0.f, dd = 0.f;
        #pragma unroll
        for (int k = 0; k < 4; ++k) {
            float4 v = srow[k]; ss += (v.x + v.y) + (v.z + v.w);
            float4 p = prow[k]; dd += (p.x + p.y) + (p.z + p.w);
        }
        pS[s][o] = ss; pD[s][o] = dd;
    }
    __syncthreads();
    float predv = 0.f;
    if (tid < SPB) {
        float ss = 0.f, dd = 0.f;
        #pragma unroll
        for (int o = 0; o < 8; ++o) { ss += pS[tid][o]; dd += pD[tid][o]; }
        float sc = 1.0f / (ss + 1e-8f);
        predv = dd * sc;                // store deferred past the barrier
        scale_lds[tid] = sc;
    }
    __syncthreads();
    if (tid < SPB) out_pred[nbase + tid] = predv;

    // ---- flush strengths + normalized, float4-coalesced (32x32 float4) ----
    #pragma unroll
    for (int it = 0; it < 4; ++it) {
        int f   = it * 256 + tid;       // float4 index over 32x32 tile
        int row = f >> 5;
        int col = f & 31;
        float4 v = *(const float4*)&SBUF[row * STR + col * 4];
        float sc = scale_lds[row];
        size_t base = ((size_t)(nbase + row)) * RR + col * 4;
        *(float4*)(out_str  + base) = v;
        *(float4*)(out_norm + base) = make_float4(v.x * sc, v.y * sc, v.z * sc, v.w * sc);
    }
}

extern "C" void kernel_launch(void* const* d_in, const int* in_sizes, int n_in,
                              void* d_out, int out_size, void* d_ws, size_t ws_size,
                              hipStream_t stream) {
    const float* X = (const float*)d_in[0];
    const float* A = (const float*)d_in[1];
    const float* B = (const float*)d_in[2];
    const float* C = (const float*)d_in[3];

    float* pred = (float*)d_out;
    float* str  = pred + NS;
    float* nrm  = str + (size_t)NS * RR;

    anfis_main<<<dim3(NBLK), dim3(256), 0, stream>>>(X, A, B, C, pred, str, nrm);
}